// Round 14
// baseline (497.564 us; speedup 1.0000x reference)
//
#include <hip/hip_runtime.h>
#include <hip/hip_bf16.h>

#define U_CNT 200000
#define I_CNT 100000
#define N_CNT 300000
#define E_CNT 1000000
#define ATTR_D 8
#define H_DIM 32
#define IB 128                               // items per item-block
#define NB_I ((I_CNT + IB - 1) / IB)         // 782 item blocks
#define XP 130                               // sXT pitch (bf16 elems)

// binning parameters
#define BSHIFT 10                            // 1024 nodes per bucket
#define NBUCK 293                            // ceil(300000/1024)
#define BCAP 12288                           // entries capacity/bucket (= 12*1024)
#define EPB 2048                             // edges per bin1 block
#define NB_BIN1 ((E_CNT + EPB - 1) / EPB)    // 489
#define NB_META5 (I_CNT / 32)                // 3125 meta-role blocks (512 thr)

// NOTE (rounds 1-4): all float inputs / output FLOAT32. absmax floor 1.95e-3
// == bf16 rounding of reference; threshold 1.26e-2.
// NOTE (round 7): rank-capture scatter + y-space reform. 1098 -> 951 us.
// NOTE (round 9): bf16 y-storage. round 10: k_prop multi-node/wave. GATHERS
// = latency x concurrency (in-flight rows per wave is the lever).
// NOTE (round 11): fusing latency-bound role with BIG-LDS role regressed.
// NOTE (round 12): per-thread batching regressed for ATOMICS.
// NOTE (round 15): 2-phase bucket binning CSR build. 615 -> 547.
// NOTE (round 17): fusion pass (deg->bin2, final_sum->prop_fin). 550 -> 513.
// NOTE (round 18): 8 nodes/wave prop + meta-role in bin1. 513 -> 499.
// NOTE (round 19): bin2 single-pass (reg-resident entries) + clamped always-8
// prop batches. 499 -> 480; prop_fin 3.95 TB/s, occ 41%.
// NOTE (round 20, this round): concurrency arithmetic: need ~5MB in flight
// to cover HBM latency; at 13 waves/CU x 1KB/wave we hold ~3.3MB. Pair
// nodes per lane-group (16 nodes/wave): two 8-entry clamped batches issued
// back-to-back -> 16 gathers (2KB) in flight per wave before accumulate.
// ~130 VGPR (all compile-time-indexed), self/store rows stay contiguous.

typedef unsigned short ubf;

__device__ __forceinline__ float b2f(ubf b) {
    return __uint_as_float((unsigned)b << 16);
}
__device__ __forceinline__ ubf f2b(float v) {
    unsigned u = __float_as_uint(v);
    u += 0x7fffu + ((u >> 16) & 1u);           // round to nearest even
    return (ubf)(u >> 16);
}
__device__ __forceinline__ unsigned pk2(float lo, float hi) {
    return (unsigned)f2b(lo) | ((unsigned)f2b(hi) << 16);
}
// unpack 8 bf16 (uint4) -> 8 f32
__device__ __forceinline__ void unpack8(uint4 g, float f[8]) {
    f[0] = __uint_as_float(g.x << 16); f[1] = __uint_as_float(g.x & 0xffff0000u);
    f[2] = __uint_as_float(g.y << 16); f[3] = __uint_as_float(g.y & 0xffff0000u);
    f[4] = __uint_as_float(g.z << 16); f[5] = __uint_as_float(g.z & 0xffff0000u);
    f[6] = __uint_as_float(g.w << 16); f[7] = __uint_as_float(g.w & 0xffff0000u);
}
// entry pack: x = key[0:19) | (partner&0x1FFF)<<19 ; y = partner>>13 | wb<<16
__device__ __forceinline__ uint2 packE(int key, int partner, unsigned wb) {
    return make_uint2((unsigned)key | (((unsigned)partner & 0x1FFFu) << 19),
                     ((unsigned)partner >> 13) | (wb << 16));
}

// ---------------- phase 1: edge MLP + binning | meta-gather role ----------------
__global__ void __launch_bounds__(512)
k_bin1(const int* __restrict__ src, const int* __restrict__ dst,
       const float* __restrict__ attr,
       const float* __restrict__ W1, const float* __restrict__ b1,
       const float* __restrict__ W2, const float* __restrict__ b2,
       uint2* __restrict__ ebuf, int* __restrict__ gcur,
       const float* __restrict__ art, const float* __restrict__ alb,
       const int* __restrict__ aid, const int* __restrict__ alid,
       ubf* __restrict__ metabuf) {
    __shared__ float sW1[ATTR_D * H_DIM];
    __shared__ float sb1[H_DIM];
    __shared__ float sW2[H_DIM];
    __shared__ float sb2;
    __shared__ int hist[NBUCK];
    __shared__ int basem[NBUCK];
    int t = threadIdx.x;
    int bx = blockIdx.x;
    if (bx >= NB_BIN1) {
        // -------- meta role: 4 items/wave, 16 lanes/item, float4/lane --------
        int lane = t & 63;
        int g = lane >> 4;
        int q = lane & 15;
        int wv = ((bx - NB_BIN1) * 512 + t) >> 6;
        int it = wv * 4 + g;                 // exact: NB_META5*8 waves * 4 = I_CNT
        if (it >= I_CNT) return;
        int a_ = aid[it], al_ = alid[it];
        float4 va = *(const float4*)&art[(size_t)a_ * 64 + q * 4];
        float4 vb = *(const float4*)&alb[(size_t)al_ * 64 + q * 4];
        ushort4 o = make_ushort4(f2b(va.x + vb.x), f2b(va.y + vb.y),
                                 f2b(va.z + vb.z), f2b(va.w + vb.w));
        *(ushort4*)&metabuf[(size_t)it * 64 + q * 4] = o;
        return;
    }
    // -------- bin1 role --------
    if (t < 256) sW1[t] = W1[t];
    if (t < H_DIM) { sb1[t] = b1[t]; sW2[t] = W2[t]; }
    if (t == 0) sb2 = b2[0];
    for (int i = t; i < NBUCK; i += 512) hist[i] = 0;
    __syncthreads();
    int ebase = bx * EPB;
    int sarr[4], darr[4];
    unsigned warr[4];
    #pragma unroll
    for (int k = 0; k < 4; ++k) {
        int e = ebase + k * 512 + t;
        sarr[k] = -1;
        if (e < E_CNT) {
            const float4* a4 = (const float4*)attr + (size_t)e * 2;
            float4 r0 = a4[0];
            float4 r1 = a4[1];
            float a[8] = {r0.x, r0.y, r0.z, r0.w, r1.x, r1.y, r1.z, r1.w};
            float z = sb2;
            #pragma unroll
            for (int h = 0; h < H_DIM; ++h) {
                float acc = sb1[h];
                #pragma unroll
                for (int kk = 0; kk < 8; ++kk) acc = fmaf(a[kk], sW1[kk * H_DIM + h], acc);
                acc = fmaxf(acc, 0.0f);
                z = fmaf(acc, sW2[h], z);
            }
            float w = 1.0f / (1.0f + __expf(-z));
            w = fmaxf(w, 1e-6f);
            int s = src[e], d = U_CNT + dst[e];
            sarr[k] = s; darr[k] = d; warr[k] = (unsigned)f2b(w);
            atomicAdd(&hist[s >> BSHIFT], 1);
            atomicAdd(&hist[d >> BSHIFT], 1);
        }
    }
    __syncthreads();
    for (int i = t; i < NBUCK; i += 512) {
        int h = hist[i];
        basem[i] = (h > 0) ? (i * BCAP + atomicAdd(&gcur[i], h)) : 0;
    }
    __syncthreads();
    for (int i = t; i < NBUCK; i += 512) hist[i] = 0;   // reuse as cursor
    __syncthreads();
    #pragma unroll
    for (int k = 0; k < 4; ++k) {
        if (sarr[k] >= 0) {
            int s = sarr[k], d = darr[k];
            unsigned wb = warr[k];
            int bs = s >> BSHIFT;
            int r = atomicAdd(&hist[bs], 1);
            ebuf[(size_t)basem[bs] + r] = packE(s, d, wb);
            int bd = d >> BSHIFT;
            r = atomicAdd(&hist[bd], 1);
            ebuf[(size_t)basem[bd] + r] = packE(d, s, wb);
        }
    }
}

// ---------------- phase 2: per-bucket CSR build, single ebuf pass ----------------
__global__ void __launch_bounds__(1024)
k_bin2(const uint2* __restrict__ ebuf, const int* __restrict__ gcur,
       int* __restrict__ offs, int2* __restrict__ csr,
       float* __restrict__ dis) {
    __shared__ int ldsCnt[NBUCK];
    __shared__ int ldsH[1024];
    __shared__ int ldsC[1024];
    __shared__ float ldsW[1024];
    __shared__ int ldsT[16];
    __shared__ int sMeta[2];          // csr_base, mycount
    int t = threadIdx.x;
    int b = blockIdx.x;
    if (t < NBUCK) ldsCnt[t] = gcur[t];   // gcur is delta-based: == count
    ldsH[t] = 0;
    ldsC[t] = 0;
    ldsW[t] = 0.0f;
    __syncthreads();
    if (t == 0) {
        int base = 0;
        for (int i = 0; i < b; ++i) base += ldsCnt[i];
        sMeta[0] = base;
        sMeta[1] = ldsCnt[b];
    }
    __syncthreads();
    int csr_base = sMeta[0], mycount = sMeta[1];
    size_t eb = (size_t)b * BCAP;
    int first = b << BSHIFT;
    // single global read: entries register-resident (<=12/thread, unrolled)
    uint2 ent[12];
    #pragma unroll
    for (int i = 0; i < 12; ++i) {
        int idx = i * 1024 + t;
        if (idx < mycount) ent[i] = ebuf[eb + idx];
    }
    // node histogram from registers
    #pragma unroll
    for (int i = 0; i < 12; ++i) {
        int idx = i * 1024 + t;
        if (idx < mycount) atomicAdd(&ldsH[(ent[i].x & 0x7FFFFu) - first], 1);
    }
    __syncthreads();
    // exclusive scan of 1024 counters: wave shfl scan + 16 wave-sums
    int v0 = ldsH[t];
    int incl = v0;
    #pragma unroll
    for (int off = 1; off < 64; off <<= 1) {
        int x = __shfl_up(incl, off, 64);
        if ((t & 63) >= off) incl += x;
    }
    int w = t >> 6;
    if ((t & 63) == 63) ldsT[w] = incl;
    __syncthreads();
    if (t == 0) {
        int run = 0;
        #pragma unroll
        for (int i = 0; i < 16; ++i) { int x = ldsT[i]; ldsT[i] = run; run += x; }
    }
    __syncthreads();
    int excl = ldsT[w] + incl - v0;
    ldsH[t] = excl;                   // ldsH now exclusive offsets
    __syncthreads();
    int ncnt = min(1024, N_CNT - first);
    if (t < ncnt) offs[first + t] = csr_base + ldsH[t];
    if (b == NBUCK - 1 && t == 0) offs[N_CNT] = 2 * E_CNT;
    // scatter register entries to final CSR + accumulate deg in LDS
    #pragma unroll
    for (int i = 0; i < 12; ++i) {
        int idx = i * 1024 + t;
        if (idx < mycount) {
            uint2 en = ent[i];
            int key = (int)(en.x & 0x7FFFFu);
            int partner = (int)((en.x >> 19) | ((en.y & 0xFFFFu) << 13));
            unsigned wb = en.y >> 16;
            int li = key - first;
            int r = atomicAdd(&ldsC[li], 1);
            csr[csr_base + ldsH[li] + r] = make_int2(partner, (int)(wb << 16));
            atomicAdd(&ldsW[li], b2f((ubf)wb));
        }
    }
    __syncthreads();
    if (t < ncnt) dis[first + t] = rsqrtf(1.0f + ldsW[t]);   // self loop = 1
}

// ---------------- users: y0 = dis * l2norm(user_w) ----------------
__global__ void k_users(const float* __restrict__ user_w, const float* __restrict__ dis,
                        ubf* __restrict__ y0, float* __restrict__ acc, int use_acc) {
    int lane = threadIdx.x & 63;
    int wv = (blockIdx.x * blockDim.x + threadIdx.x) >> 6;
    int nw = (gridDim.x * blockDim.x) >> 6;
    for (int r = wv; r < U_CNT; r += nw) {
        int idx = r * 64 + lane;
        float v = user_w[idx];
        float ss = v * v;
        #pragma unroll
        for (int m = 32; m >= 1; m >>= 1) ss += __shfl_xor(ss, m, 64);
        float inv = dis[r] / fmaxf(sqrtf(ss), 1e-12f);
        float o = v * inv;
        y0[idx] = f2b(o);
        if (use_acc) acc[idx] = o;
    }
}

// ---------------- items: pure-streaming bf16-LDS GEMM, 4 items x 8 outs ----------------
__global__ void __launch_bounds__(256)
k_items(const float* __restrict__ audio, const ubf* __restrict__ metabuf,
        const float* __restrict__ Wp, const float* __restrict__ bp,
        const float* __restrict__ dis,
        ubf* __restrict__ yitem, float* __restrict__ accitem, int use_acc) {
    __shared__ __align__(16) ubf sXT[128 * XP];
    __shared__ __align__(16) ubf sW[128 * 64];
    int t = threadIdx.x;
    int base = blockIdx.x * IB;
    // stage Wp -> bf16
    {
        const float4* wg = (const float4*)Wp;
        #pragma unroll
        for (int r = 0; r < 8; ++r) {
            int idx = r * 256 + t;
            float4 v = wg[idx];
            ushort4 o = make_ushort4(f2b(v.x), f2b(v.y), f2b(v.z), f2b(v.w));
            *(ushort4*)&sW[idx * 4] = o;
        }
    }
    // stage audio -> sXT[f][i] transposed
    {
        const float4* g = (const float4*)audio + (size_t)base * 16;
        #pragma unroll
        for (int r = 0; r < 8; ++r) {
            int idx = r * 256 + t;               // 0..2047
            int i = idx >> 4, fq = idx & 15;
            float4 v = make_float4(0.f, 0.f, 0.f, 0.f);
            if (base + i < I_CNT) v = g[idx];
            sXT[(4 * fq + 0) * XP + i] = f2b(v.x);
            sXT[(4 * fq + 1) * XP + i] = f2b(v.y);
            sXT[(4 * fq + 2) * XP + i] = f2b(v.z);
            sXT[(4 * fq + 3) * XP + i] = f2b(v.w);
        }
    }
    // stage metabuf -> sXT[64+f][i]
    {
        const uint4* m4 = (const uint4*)(metabuf + (size_t)base * 64);
        #pragma unroll
        for (int r = 0; r < 4; ++r) {
            int idx = r * 256 + t;               // 0..1023
            int i = idx >> 3, c = idx & 7;
            uint4 m = make_uint4(0u, 0u, 0u, 0u);
            if (base + i < I_CNT) m = m4[idx];
            ubf* dp = &sXT[(64 + 8 * c) * XP + i];
            dp[0 * XP] = (ubf)(m.x & 0xffffu); dp[1 * XP] = (ubf)(m.x >> 16);
            dp[2 * XP] = (ubf)(m.y & 0xffffu); dp[3 * XP] = (ubf)(m.y >> 16);
            dp[4 * XP] = (ubf)(m.z & 0xffffu); dp[5 * XP] = (ubf)(m.z >> 16);
            dp[6 * XP] = (ubf)(m.w & 0xffffu); dp[7 * XP] = (ubf)(m.w >> 16);
        }
    }
    __syncthreads();
    int og = t & 7;                      // outs 8og..8og+7
    int igr = t >> 3;                    // items 4igr..4igr+3
    float c[4][8];
    {
        float bv[8];
        #pragma unroll
        for (int j = 0; j < 8; ++j) bv[j] = bp[8 * og + j];
        #pragma unroll
        for (int i = 0; i < 4; ++i)
            #pragma unroll
            for (int j = 0; j < 8; ++j) c[i][j] = bv[j];
    }
    const ubf* xcol = &sXT[4 * igr];
    const ubf* wrow = &sW[8 * og];
    #pragma unroll 2
    for (int k = 0; k < 128; ++k) {
        ushort4 xu = *(const ushort4*)&xcol[k * XP];
        uint4 wu = *(const uint4*)&wrow[k * 64];
        float x[4] = {b2f(xu.x), b2f(xu.y), b2f(xu.z), b2f(xu.w)};
        float w[8];
        unpack8(wu, w);
        #pragma unroll
        for (int i = 0; i < 4; ++i)
            #pragma unroll
            for (int j = 0; j < 8; ++j) c[i][j] = fmaf(x[i], w[j], c[i][j]);
    }
    #pragma unroll
    for (int i = 0; i < 4; ++i) {
        float ss = 0.f;
        #pragma unroll
        for (int j = 0; j < 8; ++j) ss += c[i][j] * c[i][j];
        ss += __shfl_xor(ss, 1, 64);
        ss += __shfl_xor(ss, 2, 64);
        ss += __shfl_xor(ss, 4, 64);
        int it = base + 4 * igr + i;
        if (it < I_CNT) {
            float q = dis[U_CNT + it] / fmaxf(sqrtf(ss), 1e-12f);
            uint4 o;
            o.x = pk2(c[i][0] * q, c[i][1] * q);
            o.y = pk2(c[i][2] * q, c[i][3] * q);
            o.z = pk2(c[i][4] * q, c[i][5] * q);
            o.w = pk2(c[i][6] * q, c[i][7] * q);
            *(uint4*)&yitem[(size_t)it * 64 + 8 * og] = o;
            if (use_acc) {
                float4* ap = (float4*)&accitem[(size_t)it * 64 + 8 * og];
                ap[0] = make_float4(c[i][0] * q, c[i][1] * q, c[i][2] * q, c[i][3] * q);
                ap[1] = make_float4(c[i][4] * q, c[i][5] * q, c[i][6] * q, c[i][7] * q);
            }
        }
    }
}

// ---------------- paired-node gather machinery ----------------
struct Batch {
    int2 cc[8];
    uint4 gg[8];
};
__device__ __forceinline__ void b8_load(const int2* __restrict__ csr,
                                        const ubf* __restrict__ yin,
                                        int e, int last, int s8, Batch& B) {
    #pragma unroll
    for (int k = 0; k < 8; ++k) B.cc[k] = csr[min(e + k, last)];
    #pragma unroll
    for (int k = 0; k < 8; ++k)
        B.gg[k] = *(const uint4*)&yin[(size_t)B.cc[k].x * 64 + s8];
}
__device__ __forceinline__ void b8_acc(int e, int end, Batch& B,
                                       float* acc, float* bcc) {
    #pragma unroll
    for (int k = 0; k < 8; ++k) {
        float w = (e + k < end) ? __int_as_float(B.cc[k].y) : 0.f;
        float f[8];
        unpack8(B.gg[k], f);
        if (k & 1) {
            #pragma unroll
            for (int i = 0; i < 8; ++i) bcc[i] = fmaf(w, f[i], bcc[i]);
        } else {
            #pragma unroll
            for (int i = 0; i < 8; ++i) acc[i] = fmaf(w, f[i], acc[i]);
        }
    }
}
// gathers for two nodes co-issued: 16 rows in flight per lane-group
__device__ __forceinline__ void prop_gather2(const int* __restrict__ offs,
                                             const int2* __restrict__ csr,
                                             const ubf* __restrict__ yin,
                                             int c0, bool v1, int c1, int s8,
                                             float* r0, float* r1) {
    float a0[8], b0[8], a1[8], b1[8];
    #pragma unroll
    for (int i = 0; i < 8; ++i) { a0[i] = 0.f; b0[i] = 0.f; a1[i] = 0.f; b1[i] = 0.f; }
    int e0 = offs[c0], end0 = offs[c0 + 1];
    int e1 = v1 ? offs[c1] : 0, end1 = v1 ? offs[c1 + 1] : 0;
    int last0 = end0 - 1, last1 = end1 - 1;
    while (e0 < end0 && e1 < end1) {
        Batch A, B;
        b8_load(csr, yin, e0, last0, s8, A);
        b8_load(csr, yin, e1, last1, s8, B);
        b8_acc(e0, end0, A, a0, b0);
        b8_acc(e1, end1, B, a1, b1);
        e0 += 8; e1 += 8;
    }
    while (e0 < end0) {
        Batch A;
        b8_load(csr, yin, e0, last0, s8, A);
        b8_acc(e0, end0, A, a0, b0);
        e0 += 8;
    }
    while (e1 < end1) {
        Batch B;
        b8_load(csr, yin, e1, last1, s8, B);
        b8_acc(e1, end1, B, a1, b1);
        e1 += 8;
    }
    #pragma unroll
    for (int i = 0; i < 8; ++i) { r0[i] = a0[i] + b0[i]; r1[i] = a1[i] + b1[i]; }
}

// ---------------- LGConv round: 16 nodes/wave (pair per 8-lane group) ----------------
__global__ void k_prop(const int* __restrict__ offs, const int2* __restrict__ csr,
                       const float* __restrict__ dis,
                       const ubf* __restrict__ yin, ubf* __restrict__ yout,
                       float* __restrict__ acc, int use_acc) {
    int lane = threadIdx.x & 63;
    int g = lane >> 3;                   // group 0..7
    int s8 = (lane & 7) * 8;             // dims s8..s8+7
    int wv = (blockIdx.x * 256 + threadIdx.x) >> 6;
    int c0 = wv * 16 + g;
    int c1 = c0 + 8;
    if (c0 >= N_CNT) return;
    bool v1 = (c1 < N_CNT);
    float a0[8], a1[8];
    prop_gather2(offs, csr, yin, c0, v1, c1, s8, a0, a1);
    // node c0
    {
        float dc = dis[c0];
        size_t idx = (size_t)c0 * 64 + s8;
        uint4 sv = *(const uint4*)&yin[idx];
        float sf[8];
        unpack8(sv, sf);
        float dc2 = dc * dc;
        float r[8];
        #pragma unroll
        for (int i = 0; i < 8; ++i) r[i] = dc2 * (a0[i] + sf[i]);
        uint4 o;
        o.x = pk2(r[0], r[1]); o.y = pk2(r[2], r[3]);
        o.z = pk2(r[4], r[5]); o.w = pk2(r[6], r[7]);
        *(uint4*)&yout[idx] = o;
        if (use_acc) {
            float4* ap = (float4*)&acc[idx];
            float4 q0 = ap[0], q1 = ap[1];
            q0.x += r[0]; q0.y += r[1]; q0.z += r[2]; q0.w += r[3];
            q1.x += r[4]; q1.y += r[5]; q1.z += r[6]; q1.w += r[7];
            ap[0] = q0; ap[1] = q1;
        }
    }
    // node c1
    if (v1) {
        float dc = dis[c1];
        size_t idx = (size_t)c1 * 64 + s8;
        uint4 sv = *(const uint4*)&yin[idx];
        float sf[8];
        unpack8(sv, sf);
        float dc2 = dc * dc;
        float r[8];
        #pragma unroll
        for (int i = 0; i < 8; ++i) r[i] = dc2 * (a1[i] + sf[i]);
        uint4 o;
        o.x = pk2(r[0], r[1]); o.y = pk2(r[2], r[3]);
        o.z = pk2(r[4], r[5]); o.w = pk2(r[6], r[7]);
        *(uint4*)&yout[idx] = o;
        if (use_acc) {
            float4* ap = (float4*)&acc[idx];
            float4 q0 = ap[0], q1 = ap[1];
            q0.x += r[0]; q0.y += r[1]; q0.z += r[2]; q0.w += r[3];
            q1.x += r[4]; q1.y += r[5]; q1.z += r[6]; q1.w += r[7];
            ap[0] = q0; ap[1] = q1;
        }
    }
}

// ---------------- final round fused with layer-sum + l2norm epilogue ----------------
__global__ void k_prop_fin(const int* __restrict__ offs, const int2* __restrict__ csr,
                           const float* __restrict__ dis,
                           const ubf* __restrict__ y0, const ubf* __restrict__ y1,
                           const ubf* __restrict__ yin, float* __restrict__ out) {
    int lane = threadIdx.x & 63;
    int g = lane >> 3;
    int s8 = (lane & 7) * 8;
    int wv = (blockIdx.x * 256 + threadIdx.x) >> 6;
    int c0 = wv * 16 + g;
    int c1 = c0 + 8;
    if (c0 >= N_CNT) return;
    bool v1 = (c1 < N_CNT);
    float a0[8], a1[8];
    prop_gather2(offs, csr, yin, c0, v1, c1, s8, a0, a1);
    // node c0
    {
        float dc = dis[c0];
        size_t idx = (size_t)c0 * 64 + s8;
        uint4 sv = *(const uint4*)&yin[idx];
        uint4 v0u = *(const uint4*)&y0[idx];
        uint4 v1u = *(const uint4*)&y1[idx];
        float sf[8], f0[8], f1[8];
        unpack8(sv, sf);
        unpack8(v0u, f0);
        unpack8(v1u, f1);
        float dc2 = dc * dc;
        float v[8];
        float ss = 0.f;
        #pragma unroll
        for (int i = 0; i < 8; ++i) {
            float r = dc2 * (a0[i] + sf[i]);       // y3 unrounded
            v[i] = (f0[i] + f1[i]) + (sf[i] + r);
            ss = fmaf(v[i], v[i], ss);
        }
        ss += __shfl_xor(ss, 1, 64);
        ss += __shfl_xor(ss, 2, 64);
        ss += __shfl_xor(ss, 4, 64);
        float inv = 1.0f / fmaxf(sqrtf(ss), 1e-12f);
        float4* op = (float4*)&out[idx];
        op[0] = make_float4(v[0] * inv, v[1] * inv, v[2] * inv, v[3] * inv);
        op[1] = make_float4(v[4] * inv, v[5] * inv, v[6] * inv, v[7] * inv);
    }
    // node c1
    if (v1) {
        float dc = dis[c1];
        size_t idx = (size_t)c1 * 64 + s8;
        uint4 sv = *(const uint4*)&yin[idx];
        uint4 v0u = *(const uint4*)&y0[idx];
        uint4 v1u = *(const uint4*)&y1[idx];
        float sf[8], f0[8], f1[8];
        unpack8(sv, sf);
        unpack8(v0u, f0);
        unpack8(v1u, f1);
        float dc2 = dc * dc;
        float v[8];
        float ss = 0.f;
        #pragma unroll
        for (int i = 0; i < 8; ++i) {
            float r = dc2 * (a1[i] + sf[i]);
            v[i] = (f0[i] + f1[i]) + (sf[i] + r);
            ss = fmaf(v[i], v[i], ss);
        }
        ss += __shfl_xor(ss, 1, 64);
        ss += __shfl_xor(ss, 2, 64);
        ss += __shfl_xor(ss, 4, 64);
        float inv = 1.0f / fmaxf(sqrtf(ss), 1e-12f);
        float4* op = (float4*)&out[idx];
        op[0] = make_float4(v[0] * inv, v[1] * inv, v[2] * inv, v[3] * inv);
        op[1] = make_float4(v[4] * inv, v[5] * inv, v[6] * inv, v[7] * inv);
    }
}

// ---------------- epilogue A: l2norm(acc)  (acc fp32, may alias out) ----------------
__global__ void k_final_acc(const float* __restrict__ acc, float* __restrict__ out) {
    int lane = threadIdx.x & 63;
    int c = (blockIdx.x * 256 + threadIdx.x) >> 6;
    if (c >= N_CNT) return;
    int idx = c * 64 + lane;
    float v = acc[idx];
    float ss = v * v;
    #pragma unroll
    for (int m = 32; m >= 1; m >>= 1) ss += __shfl_xor(ss, m, 64);
    out[idx] = v / fmaxf(sqrtf(ss), 1e-12f);
}

extern "C" void kernel_launch(void* const* d_in, const int* in_sizes, int n_in,
                              void* d_out, int out_size, void* d_ws, size_t ws_size,
                              hipStream_t stream) {
    const int*   edge_src   = (const int*)  d_in[0];
    const int*   edge_dst   = (const int*)  d_in[1];
    const float* edge_attr  = (const float*)d_in[2];
    const float* user_w     = (const float*)d_in[3];
    const float* artist_w   = (const float*)d_in[4];
    const float* album_w    = (const float*)d_in[5];
    const float* item_audio = (const float*)d_in[6];
    const int*   artist_ids = (const int*)  d_in[7];
    const int*   album_ids  = (const int*)  d_in[8];
    const float* Wp         = (const float*)d_in[9];
    const float* bp         = (const float*)d_in[10];
    const float* W1         = (const float*)d_in[11];
    const float* b1         = (const float*)d_in[12];
    const float* W2         = (const float*)d_in[13];
    const float* b2         = (const float*)d_in[14];

    char* p = (char*)d_ws;
    auto carve = [&](size_t bytes) -> void* {
        void* q = (void*)p;
        p += (bytes + 255) & ~(size_t)255;
        return q;
    };
    // common carve (~31 MB)
    float* dis    = (float*)carve((size_t)N_CNT * 4);
    int*   offs   = (int*)  carve((size_t)(N_CNT + 1) * 4);
    int*   gcur   = (int*)  carve((size_t)NBUCK * 4);
    int2*  csr    = (int2*) carve((size_t)2 * E_CNT * 8);
    ubf*   metabuf= (ubf*)  carve((size_t)I_CNT * 64 * 2);  // 12.8 MB bf16
    const size_t YB = (size_t)N_CNT * 64 * 2;      // 38.4 MB per bf16 y buffer
    const size_t EBUF = (size_t)NBUCK * BCAP * 8;  // 28.8 MB entry buffer
    size_t used = (size_t)(p - (char*)d_ws);
    // Path B (no acc RMW) needs y0,y1,y2 bf16 in ws; ebuf aliases y2 (dead
    // until prop round 2). Else ping-pong + fp32 acc in d_out.
    int no_acc = (ws_size >= used + 3 * YB + (size_t)4096) ? 1 : 0;
    ubf *y0, *y1, *y2;
    uint2* ebuf;
    float* acc = nullptr;
    if (no_acc) {
        y0 = (ubf*)carve(YB);
        y1 = (ubf*)carve(YB);
        y2 = (ubf*)carve(YB);
        ebuf = (uint2*)y2;             // alias: 38.4MB >= 28.8MB
    } else {
        y0 = (ubf*)carve(YB);
        y1 = (ubf*)carve(YB);
        y2 = y0;
        acc = (float*)d_out;           // fp32 accumulator lives in d_out
        ebuf = (uint2*)carve(EBUF);
    }
    (void)in_sizes; (void)n_in; (void)out_size;

    hipMemsetAsync(gcur, 0, (size_t)NBUCK * 4, stream);
    // bin1 blocks first (atomic-latency role), meta role blocks fill behind
    k_bin1 <<<NB_BIN1 + NB_META5, 512, 0, stream>>>(
        edge_src, edge_dst, edge_attr, W1, b1, W2, b2, ebuf, gcur,
        artist_w, album_w, artist_ids, album_ids, metabuf);
    k_bin2 <<<NBUCK, 1024, 0, stream>>>(ebuf, gcur, offs, csr, dis);
    k_users<<<1024, 256, 0, stream>>>(user_w, dis, y0, acc, no_acc ? 0 : 1);
    k_items<<<NB_I, 256, 0, stream>>>(item_audio, metabuf, Wp, bp, dis,
                                      y0 + (size_t)U_CNT * 64,
                                      no_acc ? nullptr : acc + (size_t)U_CNT * 64,
                                      no_acc ? 0 : 1);
    // 16 nodes per wave -> N/16 waves -> ceil(N/64) blocks of 256
    const int PROP_BLKS = (N_CNT + 63) / 64;     // 4688
    if (no_acc) {
        k_prop<<<PROP_BLKS, 256, 0, stream>>>(offs, csr, dis, y0, y1, nullptr, 0);
        k_prop<<<PROP_BLKS, 256, 0, stream>>>(offs, csr, dis, y1, y2, nullptr, 0);
        k_prop_fin<<<PROP_BLKS, 256, 0, stream>>>(offs, csr, dis, y0, y1, y2,
                                                  (float*)d_out);
    } else {
        // y0 -> y1 -> y0 -> y1 (bf16), accumulating fp32 into acc (= d_out)
        k_prop<<<PROP_BLKS, 256, 0, stream>>>(offs, csr, dis, y0, y1, acc, 1);
        k_prop<<<PROP_BLKS, 256, 0, stream>>>(offs, csr, dis, y1, y0, acc, 1);
        k_prop<<<PROP_BLKS, 256, 0, stream>>>(offs, csr, dis, y0, y1, acc, 1);
        k_final_acc<<<N_CNT / 4, 256, 0, stream>>>(acc, (float*)d_out);
    }
}

// Round 15
// 482.280 us; speedup vs baseline: 1.0317x; 1.0317x over previous
//
#include <hip/hip_runtime.h>
#include <hip/hip_bf16.h>

#define U_CNT 200000
#define I_CNT 100000
#define N_CNT 300000
#define E_CNT 1000000
#define ATTR_D 8
#define H_DIM 32
#define IB 128                               // items per item-block
#define NB_I ((I_CNT + IB - 1) / IB)         // 782 item blocks
#define XP 130                               // sXT pitch (bf16 elems)

// binning parameters
#define BSHIFT 10                            // 1024 nodes per bucket
#define NBUCK 293                            // ceil(300000/1024)
#define BCAP 12288                           // entries capacity/bucket (= 12*1024)
#define EPB 2048                             // edges per bin1 block
#define NB_BIN1 ((E_CNT + EPB - 1) / EPB)    // 489
#define NB_META5 (I_CNT / 32)                // 3125 meta-role blocks (512 thr)

// NOTE (rounds 1-4): all float inputs / output FLOAT32. absmax floor 1.95e-3
// == bf16 rounding of reference; threshold 1.26e-2.
// NOTE (round 7): rank-capture scatter + y-space reform. 1098 -> 951 us.
// NOTE (round 9): bf16 y-storage. round 10: k_prop multi-node/wave. GATHERS
// = latency x concurrency (in-flight rows per wave is the lever).
// NOTE (round 11): fusing latency-bound role with BIG-LDS role regressed.
// NOTE (round 12): per-thread batching regressed for ATOMICS.
// NOTE (round 15): 2-phase bucket binning CSR build. 615 -> 547.
// NOTE (round 17): fusion pass (deg->bin2, final_sum->prop_fin). 550 -> 513.
// NOTE (round 18): 8 nodes/wave prop + meta-role in bin1. 513 -> 499.
// NOTE (round 19): bin2 single-pass (reg-resident entries) + clamped always-8
// prop batches. 499 -> 480; prop_fin 3.95 TB/s (49% peak), occ 41%.
// NOTE (round 20): paired-node (16 nodes/wave) REGRESSED (480 -> 498):
// compiler allocated only 52 VGPR — it serialized the two batches instead of
// keeping both in flight, while occupancy dropped 41->32%. Lesson: source-
// level batch interleave does NOT force live registers; check VGPR count.
// NOTE (round 21, this round): revert prop family to round-19 exactly.
// Prop is at its bracketed concurrency floor (~49% HBM peak on random
// 128B-row gathers); bin1 at the scattered-atomic wall; rest near streaming
// floors.

typedef unsigned short ubf;

__device__ __forceinline__ float b2f(ubf b) {
    return __uint_as_float((unsigned)b << 16);
}
__device__ __forceinline__ ubf f2b(float v) {
    unsigned u = __float_as_uint(v);
    u += 0x7fffu + ((u >> 16) & 1u);           // round to nearest even
    return (ubf)(u >> 16);
}
__device__ __forceinline__ unsigned pk2(float lo, float hi) {
    return (unsigned)f2b(lo) | ((unsigned)f2b(hi) << 16);
}
// unpack 8 bf16 (uint4) -> 8 f32
__device__ __forceinline__ void unpack8(uint4 g, float f[8]) {
    f[0] = __uint_as_float(g.x << 16); f[1] = __uint_as_float(g.x & 0xffff0000u);
    f[2] = __uint_as_float(g.y << 16); f[3] = __uint_as_float(g.y & 0xffff0000u);
    f[4] = __uint_as_float(g.z << 16); f[5] = __uint_as_float(g.z & 0xffff0000u);
    f[6] = __uint_as_float(g.w << 16); f[7] = __uint_as_float(g.w & 0xffff0000u);
}
// entry pack: x = key[0:19) | (partner&0x1FFF)<<19 ; y = partner>>13 | wb<<16
__device__ __forceinline__ uint2 packE(int key, int partner, unsigned wb) {
    return make_uint2((unsigned)key | (((unsigned)partner & 0x1FFFu) << 19),
                     ((unsigned)partner >> 13) | (wb << 16));
}

// ---------------- phase 1: edge MLP + binning | meta-gather role ----------------
__global__ void __launch_bounds__(512)
k_bin1(const int* __restrict__ src, const int* __restrict__ dst,
       const float* __restrict__ attr,
       const float* __restrict__ W1, const float* __restrict__ b1,
       const float* __restrict__ W2, const float* __restrict__ b2,
       uint2* __restrict__ ebuf, int* __restrict__ gcur,
       const float* __restrict__ art, const float* __restrict__ alb,
       const int* __restrict__ aid, const int* __restrict__ alid,
       ubf* __restrict__ metabuf) {
    __shared__ float sW1[ATTR_D * H_DIM];
    __shared__ float sb1[H_DIM];
    __shared__ float sW2[H_DIM];
    __shared__ float sb2;
    __shared__ int hist[NBUCK];
    __shared__ int basem[NBUCK];
    int t = threadIdx.x;
    int bx = blockIdx.x;
    if (bx >= NB_BIN1) {
        // -------- meta role: 4 items/wave, 16 lanes/item, float4/lane --------
        int lane = t & 63;
        int g = lane >> 4;
        int q = lane & 15;
        int wv = ((bx - NB_BIN1) * 512 + t) >> 6;
        int it = wv * 4 + g;                 // exact: NB_META5*8 waves * 4 = I_CNT
        if (it >= I_CNT) return;
        int a_ = aid[it], al_ = alid[it];
        float4 va = *(const float4*)&art[(size_t)a_ * 64 + q * 4];
        float4 vb = *(const float4*)&alb[(size_t)al_ * 64 + q * 4];
        ushort4 o = make_ushort4(f2b(va.x + vb.x), f2b(va.y + vb.y),
                                 f2b(va.z + vb.z), f2b(va.w + vb.w));
        *(ushort4*)&metabuf[(size_t)it * 64 + q * 4] = o;
        return;
    }
    // -------- bin1 role --------
    if (t < 256) sW1[t] = W1[t];
    if (t < H_DIM) { sb1[t] = b1[t]; sW2[t] = W2[t]; }
    if (t == 0) sb2 = b2[0];
    for (int i = t; i < NBUCK; i += 512) hist[i] = 0;
    __syncthreads();
    int ebase = bx * EPB;
    int sarr[4], darr[4];
    unsigned warr[4];
    #pragma unroll
    for (int k = 0; k < 4; ++k) {
        int e = ebase + k * 512 + t;
        sarr[k] = -1;
        if (e < E_CNT) {
            const float4* a4 = (const float4*)attr + (size_t)e * 2;
            float4 r0 = a4[0];
            float4 r1 = a4[1];
            float a[8] = {r0.x, r0.y, r0.z, r0.w, r1.x, r1.y, r1.z, r1.w};
            float z = sb2;
            #pragma unroll
            for (int h = 0; h < H_DIM; ++h) {
                float acc = sb1[h];
                #pragma unroll
                for (int kk = 0; kk < 8; ++kk) acc = fmaf(a[kk], sW1[kk * H_DIM + h], acc);
                acc = fmaxf(acc, 0.0f);
                z = fmaf(acc, sW2[h], z);
            }
            float w = 1.0f / (1.0f + __expf(-z));
            w = fmaxf(w, 1e-6f);
            int s = src[e], d = U_CNT + dst[e];
            sarr[k] = s; darr[k] = d; warr[k] = (unsigned)f2b(w);
            atomicAdd(&hist[s >> BSHIFT], 1);
            atomicAdd(&hist[d >> BSHIFT], 1);
        }
    }
    __syncthreads();
    for (int i = t; i < NBUCK; i += 512) {
        int h = hist[i];
        basem[i] = (h > 0) ? (i * BCAP + atomicAdd(&gcur[i], h)) : 0;
    }
    __syncthreads();
    for (int i = t; i < NBUCK; i += 512) hist[i] = 0;   // reuse as cursor
    __syncthreads();
    #pragma unroll
    for (int k = 0; k < 4; ++k) {
        if (sarr[k] >= 0) {
            int s = sarr[k], d = darr[k];
            unsigned wb = warr[k];
            int bs = s >> BSHIFT;
            int r = atomicAdd(&hist[bs], 1);
            ebuf[(size_t)basem[bs] + r] = packE(s, d, wb);
            int bd = d >> BSHIFT;
            r = atomicAdd(&hist[bd], 1);
            ebuf[(size_t)basem[bd] + r] = packE(d, s, wb);
        }
    }
}

// ---------------- phase 2: per-bucket CSR build, single ebuf pass ----------------
__global__ void __launch_bounds__(1024)
k_bin2(const uint2* __restrict__ ebuf, const int* __restrict__ gcur,
       int* __restrict__ offs, int2* __restrict__ csr,
       float* __restrict__ dis) {
    __shared__ int ldsCnt[NBUCK];
    __shared__ int ldsH[1024];
    __shared__ int ldsC[1024];
    __shared__ float ldsW[1024];
    __shared__ int ldsT[16];
    __shared__ int sMeta[2];          // csr_base, mycount
    int t = threadIdx.x;
    int b = blockIdx.x;
    if (t < NBUCK) ldsCnt[t] = gcur[t];   // gcur is delta-based: == count
    ldsH[t] = 0;
    ldsC[t] = 0;
    ldsW[t] = 0.0f;
    __syncthreads();
    if (t == 0) {
        int base = 0;
        for (int i = 0; i < b; ++i) base += ldsCnt[i];
        sMeta[0] = base;
        sMeta[1] = ldsCnt[b];
    }
    __syncthreads();
    int csr_base = sMeta[0], mycount = sMeta[1];
    size_t eb = (size_t)b * BCAP;
    int first = b << BSHIFT;
    // single global read: entries register-resident (<=12/thread, unrolled)
    uint2 ent[12];
    #pragma unroll
    for (int i = 0; i < 12; ++i) {
        int idx = i * 1024 + t;
        if (idx < mycount) ent[i] = ebuf[eb + idx];
    }
    // node histogram from registers
    #pragma unroll
    for (int i = 0; i < 12; ++i) {
        int idx = i * 1024 + t;
        if (idx < mycount) atomicAdd(&ldsH[(ent[i].x & 0x7FFFFu) - first], 1);
    }
    __syncthreads();
    // exclusive scan of 1024 counters: wave shfl scan + 16 wave-sums
    int v0 = ldsH[t];
    int incl = v0;
    #pragma unroll
    for (int off = 1; off < 64; off <<= 1) {
        int x = __shfl_up(incl, off, 64);
        if ((t & 63) >= off) incl += x;
    }
    int w = t >> 6;
    if ((t & 63) == 63) ldsT[w] = incl;
    __syncthreads();
    if (t == 0) {
        int run = 0;
        #pragma unroll
        for (int i = 0; i < 16; ++i) { int x = ldsT[i]; ldsT[i] = run; run += x; }
    }
    __syncthreads();
    int excl = ldsT[w] + incl - v0;
    ldsH[t] = excl;                   // ldsH now exclusive offsets
    __syncthreads();
    int ncnt = min(1024, N_CNT - first);
    if (t < ncnt) offs[first + t] = csr_base + ldsH[t];
    if (b == NBUCK - 1 && t == 0) offs[N_CNT] = 2 * E_CNT;
    // scatter register entries to final CSR + accumulate deg in LDS
    #pragma unroll
    for (int i = 0; i < 12; ++i) {
        int idx = i * 1024 + t;
        if (idx < mycount) {
            uint2 en = ent[i];
            int key = (int)(en.x & 0x7FFFFu);
            int partner = (int)((en.x >> 19) | ((en.y & 0xFFFFu) << 13));
            unsigned wb = en.y >> 16;
            int li = key - first;
            int r = atomicAdd(&ldsC[li], 1);
            csr[csr_base + ldsH[li] + r] = make_int2(partner, (int)(wb << 16));
            atomicAdd(&ldsW[li], b2f((ubf)wb));
        }
    }
    __syncthreads();
    if (t < ncnt) dis[first + t] = rsqrtf(1.0f + ldsW[t]);   // self loop = 1
}

// ---------------- users: y0 = dis * l2norm(user_w) ----------------
__global__ void k_users(const float* __restrict__ user_w, const float* __restrict__ dis,
                        ubf* __restrict__ y0, float* __restrict__ acc, int use_acc) {
    int lane = threadIdx.x & 63;
    int wv = (blockIdx.x * blockDim.x + threadIdx.x) >> 6;
    int nw = (gridDim.x * blockDim.x) >> 6;
    for (int r = wv; r < U_CNT; r += nw) {
        int idx = r * 64 + lane;
        float v = user_w[idx];
        float ss = v * v;
        #pragma unroll
        for (int m = 32; m >= 1; m >>= 1) ss += __shfl_xor(ss, m, 64);
        float inv = dis[r] / fmaxf(sqrtf(ss), 1e-12f);
        float o = v * inv;
        y0[idx] = f2b(o);
        if (use_acc) acc[idx] = o;
    }
}

// ---------------- items: pure-streaming bf16-LDS GEMM, 4 items x 8 outs ----------------
__global__ void __launch_bounds__(256)
k_items(const float* __restrict__ audio, const ubf* __restrict__ metabuf,
        const float* __restrict__ Wp, const float* __restrict__ bp,
        const float* __restrict__ dis,
        ubf* __restrict__ yitem, float* __restrict__ accitem, int use_acc) {
    __shared__ __align__(16) ubf sXT[128 * XP];
    __shared__ __align__(16) ubf sW[128 * 64];
    int t = threadIdx.x;
    int base = blockIdx.x * IB;
    // stage Wp -> bf16
    {
        const float4* wg = (const float4*)Wp;
        #pragma unroll
        for (int r = 0; r < 8; ++r) {
            int idx = r * 256 + t;
            float4 v = wg[idx];
            ushort4 o = make_ushort4(f2b(v.x), f2b(v.y), f2b(v.z), f2b(v.w));
            *(ushort4*)&sW[idx * 4] = o;
        }
    }
    // stage audio -> sXT[f][i] transposed
    {
        const float4* g = (const float4*)audio + (size_t)base * 16;
        #pragma unroll
        for (int r = 0; r < 8; ++r) {
            int idx = r * 256 + t;               // 0..2047
            int i = idx >> 4, fq = idx & 15;
            float4 v = make_float4(0.f, 0.f, 0.f, 0.f);
            if (base + i < I_CNT) v = g[idx];
            sXT[(4 * fq + 0) * XP + i] = f2b(v.x);
            sXT[(4 * fq + 1) * XP + i] = f2b(v.y);
            sXT[(4 * fq + 2) * XP + i] = f2b(v.z);
            sXT[(4 * fq + 3) * XP + i] = f2b(v.w);
        }
    }
    // stage metabuf -> sXT[64+f][i]
    {
        const uint4* m4 = (const uint4*)(metabuf + (size_t)base * 64);
        #pragma unroll
        for (int r = 0; r < 4; ++r) {
            int idx = r * 256 + t;               // 0..1023
            int i = idx >> 3, c = idx & 7;
            uint4 m = make_uint4(0u, 0u, 0u, 0u);
            if (base + i < I_CNT) m = m4[idx];
            ubf* dp = &sXT[(64 + 8 * c) * XP + i];
            dp[0 * XP] = (ubf)(m.x & 0xffffu); dp[1 * XP] = (ubf)(m.x >> 16);
            dp[2 * XP] = (ubf)(m.y & 0xffffu); dp[3 * XP] = (ubf)(m.y >> 16);
            dp[4 * XP] = (ubf)(m.z & 0xffffu); dp[5 * XP] = (ubf)(m.z >> 16);
            dp[6 * XP] = (ubf)(m.w & 0xffffu); dp[7 * XP] = (ubf)(m.w >> 16);
        }
    }
    __syncthreads();
    int og = t & 7;                      // outs 8og..8og+7
    int igr = t >> 3;                    // items 4igr..4igr+3
    float c[4][8];
    {
        float bv[8];
        #pragma unroll
        for (int j = 0; j < 8; ++j) bv[j] = bp[8 * og + j];
        #pragma unroll
        for (int i = 0; i < 4; ++i)
            #pragma unroll
            for (int j = 0; j < 8; ++j) c[i][j] = bv[j];
    }
    const ubf* xcol = &sXT[4 * igr];
    const ubf* wrow = &sW[8 * og];
    #pragma unroll 2
    for (int k = 0; k < 128; ++k) {
        ushort4 xu = *(const ushort4*)&xcol[k * XP];
        uint4 wu = *(const uint4*)&wrow[k * 64];
        float x[4] = {b2f(xu.x), b2f(xu.y), b2f(xu.z), b2f(xu.w)};
        float w[8];
        unpack8(wu, w);
        #pragma unroll
        for (int i = 0; i < 4; ++i)
            #pragma unroll
            for (int j = 0; j < 8; ++j) c[i][j] = fmaf(x[i], w[j], c[i][j]);
    }
    #pragma unroll
    for (int i = 0; i < 4; ++i) {
        float ss = 0.f;
        #pragma unroll
        for (int j = 0; j < 8; ++j) ss += c[i][j] * c[i][j];
        ss += __shfl_xor(ss, 1, 64);
        ss += __shfl_xor(ss, 2, 64);
        ss += __shfl_xor(ss, 4, 64);
        int it = base + 4 * igr + i;
        if (it < I_CNT) {
            float q = dis[U_CNT + it] / fmaxf(sqrtf(ss), 1e-12f);
            uint4 o;
            o.x = pk2(c[i][0] * q, c[i][1] * q);
            o.y = pk2(c[i][2] * q, c[i][3] * q);
            o.z = pk2(c[i][4] * q, c[i][5] * q);
            o.w = pk2(c[i][6] * q, c[i][7] * q);
            *(uint4*)&yitem[(size_t)it * 64 + 8 * og] = o;
            if (use_acc) {
                float4* ap = (float4*)&accitem[(size_t)it * 64 + 8 * og];
                ap[0] = make_float4(c[i][0] * q, c[i][1] * q, c[i][2] * q, c[i][3] * q);
                ap[1] = make_float4(c[i][4] * q, c[i][5] * q, c[i][6] * q, c[i][7] * q);
            }
        }
    }
}

// ---------------- gather core: 8 nodes/wave, 8 lanes/node, clamped 8-batches ----------------
__device__ __forceinline__ void prop_gather(const int* __restrict__ offs,
                                            const int2* __restrict__ csr,
                                            const ubf* __restrict__ yin,
                                            int c, int s8, float* acc) {
    int e = offs[c], end = offs[c + 1];
    float bcc[8];
    #pragma unroll
    for (int i = 0; i < 8; ++i) bcc[i] = 0.f;
    int last = end - 1;
    for (; e < end; e += 8) {
        int i1 = min(e + 1, last), i2 = min(e + 2, last), i3 = min(e + 3, last);
        int i4 = min(e + 4, last), i5 = min(e + 5, last), i6 = min(e + 6, last);
        int i7 = min(e + 7, last);
        int2 c0 = csr[e],  c1 = csr[i1], c2 = csr[i2], c3 = csr[i3];
        int2 c4 = csr[i4], c5 = csr[i5], c6 = csr[i6], c7 = csr[i7];
        uint4 g0 = *(const uint4*)&yin[(size_t)c0.x * 64 + s8];
        uint4 g1 = *(const uint4*)&yin[(size_t)c1.x * 64 + s8];
        uint4 g2 = *(const uint4*)&yin[(size_t)c2.x * 64 + s8];
        uint4 g3 = *(const uint4*)&yin[(size_t)c3.x * 64 + s8];
        uint4 g4 = *(const uint4*)&yin[(size_t)c4.x * 64 + s8];
        uint4 g5 = *(const uint4*)&yin[(size_t)c5.x * 64 + s8];
        uint4 g6 = *(const uint4*)&yin[(size_t)c6.x * 64 + s8];
        uint4 g7 = *(const uint4*)&yin[(size_t)c7.x * 64 + s8];
        float w0 = __int_as_float(c0.y);
        float w1 = (e + 1 < end) ? __int_as_float(c1.y) : 0.f;
        float w2 = (e + 2 < end) ? __int_as_float(c2.y) : 0.f;
        float w3 = (e + 3 < end) ? __int_as_float(c3.y) : 0.f;
        float w4 = (e + 4 < end) ? __int_as_float(c4.y) : 0.f;
        float w5 = (e + 5 < end) ? __int_as_float(c5.y) : 0.f;
        float w6 = (e + 6 < end) ? __int_as_float(c6.y) : 0.f;
        float w7 = (e + 7 < end) ? __int_as_float(c7.y) : 0.f;
        float f[8];
        unpack8(g0, f);
        #pragma unroll
        for (int i = 0; i < 8; ++i) acc[i] = fmaf(w0, f[i], acc[i]);
        unpack8(g1, f);
        #pragma unroll
        for (int i = 0; i < 8; ++i) bcc[i] = fmaf(w1, f[i], bcc[i]);
        unpack8(g2, f);
        #pragma unroll
        for (int i = 0; i < 8; ++i) acc[i] = fmaf(w2, f[i], acc[i]);
        unpack8(g3, f);
        #pragma unroll
        for (int i = 0; i < 8; ++i) bcc[i] = fmaf(w3, f[i], bcc[i]);
        unpack8(g4, f);
        #pragma unroll
        for (int i = 0; i < 8; ++i) acc[i] = fmaf(w4, f[i], acc[i]);
        unpack8(g5, f);
        #pragma unroll
        for (int i = 0; i < 8; ++i) bcc[i] = fmaf(w5, f[i], bcc[i]);
        unpack8(g6, f);
        #pragma unroll
        for (int i = 0; i < 8; ++i) acc[i] = fmaf(w6, f[i], acc[i]);
        unpack8(g7, f);
        #pragma unroll
        for (int i = 0; i < 8; ++i) bcc[i] = fmaf(w7, f[i], bcc[i]);
    }
    #pragma unroll
    for (int i = 0; i < 8; ++i) acc[i] += bcc[i];
}

// ---------------- LGConv round: 8 nodes/wave, 8 lanes/node ----------------
__global__ void k_prop(const int* __restrict__ offs, const int2* __restrict__ csr,
                       const float* __restrict__ dis,
                       const ubf* __restrict__ yin, ubf* __restrict__ yout,
                       float* __restrict__ acc, int use_acc) {
    int lane = threadIdx.x & 63;
    int g = lane >> 3;                   // node group 0..7
    int s8 = (lane & 7) * 8;             // dims s8..s8+7
    int wv = (blockIdx.x * 256 + threadIdx.x) >> 6;
    int c = wv * 8 + g;
    if (c >= N_CNT) return;
    float dc = dis[c];
    float a[8];
    #pragma unroll
    for (int i = 0; i < 8; ++i) a[i] = 0.f;
    prop_gather(offs, csr, yin, c, s8, a);
    size_t idx = (size_t)c * 64 + s8;
    uint4 sv = *(const uint4*)&yin[idx];
    float sf[8];
    unpack8(sv, sf);
    float dc2 = dc * dc;
    float r[8];
    #pragma unroll
    for (int i = 0; i < 8; ++i) r[i] = dc2 * (a[i] + sf[i]);
    uint4 o;
    o.x = pk2(r[0], r[1]); o.y = pk2(r[2], r[3]);
    o.z = pk2(r[4], r[5]); o.w = pk2(r[6], r[7]);
    *(uint4*)&yout[idx] = o;
    if (use_acc) {
        float4* ap = (float4*)&acc[idx];
        float4 a0 = ap[0], a1 = ap[1];
        a0.x += r[0]; a0.y += r[1]; a0.z += r[2]; a0.w += r[3];
        a1.x += r[4]; a1.y += r[5]; a1.z += r[6]; a1.w += r[7];
        ap[0] = a0; ap[1] = a1;
    }
}

// ---------------- final round fused with layer-sum + l2norm epilogue ----------------
__global__ void k_prop_fin(const int* __restrict__ offs, const int2* __restrict__ csr,
                           const float* __restrict__ dis,
                           const ubf* __restrict__ y0, const ubf* __restrict__ y1,
                           const ubf* __restrict__ yin, float* __restrict__ out) {
    int lane = threadIdx.x & 63;
    int g = lane >> 3;
    int s8 = (lane & 7) * 8;
    int wv = (blockIdx.x * 256 + threadIdx.x) >> 6;
    int c = wv * 8 + g;
    if (c >= N_CNT) return;
    float dc = dis[c];
    float a[8];
    #pragma unroll
    for (int i = 0; i < 8; ++i) a[i] = 0.f;
    prop_gather(offs, csr, yin, c, s8, a);
    size_t idx = (size_t)c * 64 + s8;
    uint4 sv = *(const uint4*)&yin[idx];
    uint4 v0u = *(const uint4*)&y0[idx];
    uint4 v1u = *(const uint4*)&y1[idx];
    float sf[8], f0[8], f1[8];
    unpack8(sv, sf);
    unpack8(v0u, f0);
    unpack8(v1u, f1);
    float dc2 = dc * dc;
    float v[8];
    float ss = 0.f;
    #pragma unroll
    for (int i = 0; i < 8; ++i) {
        float r = dc2 * (a[i] + sf[i]);            // y3 unrounded
        v[i] = (f0[i] + f1[i]) + (sf[i] + r);
        ss = fmaf(v[i], v[i], ss);
    }
    ss += __shfl_xor(ss, 1, 64);
    ss += __shfl_xor(ss, 2, 64);
    ss += __shfl_xor(ss, 4, 64);
    float inv = 1.0f / fmaxf(sqrtf(ss), 1e-12f);
    float4* op = (float4*)&out[idx];
    op[0] = make_float4(v[0] * inv, v[1] * inv, v[2] * inv, v[3] * inv);
    op[1] = make_float4(v[4] * inv, v[5] * inv, v[6] * inv, v[7] * inv);
}

// ---------------- epilogue A: l2norm(acc)  (acc fp32, may alias out) ----------------
__global__ void k_final_acc(const float* __restrict__ acc, float* __restrict__ out) {
    int lane = threadIdx.x & 63;
    int c = (blockIdx.x * 256 + threadIdx.x) >> 6;
    if (c >= N_CNT) return;
    int idx = c * 64 + lane;
    float v = acc[idx];
    float ss = v * v;
    #pragma unroll
    for (int m = 32; m >= 1; m >>= 1) ss += __shfl_xor(ss, m, 64);
    out[idx] = v / fmaxf(sqrtf(ss), 1e-12f);
}

extern "C" void kernel_launch(void* const* d_in, const int* in_sizes, int n_in,
                              void* d_out, int out_size, void* d_ws, size_t ws_size,
                              hipStream_t stream) {
    const int*   edge_src   = (const int*)  d_in[0];
    const int*   edge_dst   = (const int*)  d_in[1];
    const float* edge_attr  = (const float*)d_in[2];
    const float* user_w     = (const float*)d_in[3];
    const float* artist_w   = (const float*)d_in[4];
    const float* album_w    = (const float*)d_in[5];
    const float* item_audio = (const float*)d_in[6];
    const int*   artist_ids = (const int*)  d_in[7];
    const int*   album_ids  = (const int*)  d_in[8];
    const float* Wp         = (const float*)d_in[9];
    const float* bp         = (const float*)d_in[10];
    const float* W1         = (const float*)d_in[11];
    const float* b1         = (const float*)d_in[12];
    const float* W2         = (const float*)d_in[13];
    const float* b2         = (const float*)d_in[14];

    char* p = (char*)d_ws;
    auto carve = [&](size_t bytes) -> void* {
        void* q = (void*)p;
        p += (bytes + 255) & ~(size_t)255;
        return q;
    };
    // common carve (~31 MB)
    float* dis    = (float*)carve((size_t)N_CNT * 4);
    int*   offs   = (int*)  carve((size_t)(N_CNT + 1) * 4);
    int*   gcur   = (int*)  carve((size_t)NBUCK * 4);
    int2*  csr    = (int2*) carve((size_t)2 * E_CNT * 8);
    ubf*   metabuf= (ubf*)  carve((size_t)I_CNT * 64 * 2);  // 12.8 MB bf16
    const size_t YB = (size_t)N_CNT * 64 * 2;      // 38.4 MB per bf16 y buffer
    const size_t EBUF = (size_t)NBUCK * BCAP * 8;  // 28.8 MB entry buffer
    size_t used = (size_t)(p - (char*)d_ws);
    // Path B (no acc RMW) needs y0,y1,y2 bf16 in ws; ebuf aliases y2 (dead
    // until prop round 2). Else ping-pong + fp32 acc in d_out.
    int no_acc = (ws_size >= used + 3 * YB + (size_t)4096) ? 1 : 0;
    ubf *y0, *y1, *y2;
    uint2* ebuf;
    float* acc = nullptr;
    if (no_acc) {
        y0 = (ubf*)carve(YB);
        y1 = (ubf*)carve(YB);
        y2 = (ubf*)carve(YB);
        ebuf = (uint2*)y2;             // alias: 38.4MB >= 28.8MB
    } else {
        y0 = (ubf*)carve(YB);
        y1 = (ubf*)carve(YB);
        y2 = y0;
        acc = (float*)d_out;           // fp32 accumulator lives in d_out
        ebuf = (uint2*)carve(EBUF);
    }
    (void)in_sizes; (void)n_in; (void)out_size;

    hipMemsetAsync(gcur, 0, (size_t)NBUCK * 4, stream);
    // bin1 blocks first (atomic-latency role), meta role blocks fill behind
    k_bin1 <<<NB_BIN1 + NB_META5, 512, 0, stream>>>(
        edge_src, edge_dst, edge_attr, W1, b1, W2, b2, ebuf, gcur,
        artist_w, album_w, artist_ids, album_ids, metabuf);
    k_bin2 <<<NBUCK, 1024, 0, stream>>>(ebuf, gcur, offs, csr, dis);
    k_users<<<1024, 256, 0, stream>>>(user_w, dis, y0, acc, no_acc ? 0 : 1);
    k_items<<<NB_I, 256, 0, stream>>>(item_audio, metabuf, Wp, bp, dis,
                                      y0 + (size_t)U_CNT * 64,
                                      no_acc ? nullptr : acc + (size_t)U_CNT * 64,
                                      no_acc ? 0 : 1);
    // 8 nodes per wave -> N/8 waves -> N/32 blocks of 256
    const int PROP_BLKS = N_CNT / 32;    // 9375
    if (no_acc) {
        k_prop<<<PROP_BLKS, 256, 0, stream>>>(offs, csr, dis, y0, y1, nullptr, 0);
        k_prop<<<PROP_BLKS, 256, 0, stream>>>(offs, csr, dis, y1, y2, nullptr, 0);
        k_prop_fin<<<PROP_BLKS, 256, 0, stream>>>(offs, csr, dis, y0, y1, y2,
                                                  (float*)d_out);
    } else {
        // y0 -> y1 -> y0 -> y1 (bf16), accumulating fp32 into acc (= d_out)
        k_prop<<<PROP_BLKS, 256, 0, stream>>>(offs, csr, dis, y0, y1, acc, 1);
        k_prop<<<PROP_BLKS, 256, 0, stream>>>(offs, csr, dis, y1, y0, acc, 1);
        k_prop<<<PROP_BLKS, 256, 0, stream>>>(offs, csr, dis, y0, y1, acc, 1);
        k_final_acc<<<N_CNT / 4, 256, 0, stream>>>(acc, (float*)d_out);
    }
}